// Round 13
// baseline (64.837 us; speedup 1.0000x reference)
//
#include <hip/hip_runtime.h>
#include <float.h>

// EuclideanCodebook R13: R9 geometry + R12 ring-3 single-barrier + R7 deferred
// scoring, combined.
//  - 64 rows/wave (4 rt-tiles), wave-pair splits chunk codes (nt) -> 8 ds_read
//    : 48 MFMA per chunk per wave (1:6), 2 blocks/CU (52KB LDS).
//  - ring-3 LDS staging, ONE barrier/chunk, vmcnt(4) drains a chunk issued
//    2 iterations ago (never actually waits).
//  - deferred scoring: score chunk ch-1 AFTER issuing chunk ch's MFMAs
//    (independent acc sets) -> scoring VALU hides in the matrix shadow.
// Core: 16x16x32 f16-split (3 passes: eh*2xh, eh*2xl, el*2xh), fp32 accum,
// 4 independent acc chains. score = 2*dot - e^2 (x^2 dropped, argmax-invar).
// ws: [0: esq 4KB | 4096: fragment-ordered codebook image 512KB]

#define Cdim        128
#define KCODES      1024
#define CH          32
#define NCH         32
#define BROWS       128       // 2 row-groups x 64 rows
#define THREADS     256
#define IMG_OFF     4096
#define CHUNK_BYTES 16384     // [nt0 hi 4K | nt1 hi 4K | nt0 lo 4K | nt1 lo 4K]

typedef _Float16 f16;
typedef __attribute__((ext_vector_type(8))) _Float16 f16x8;
typedef __attribute__((ext_vector_type(4))) float    f32x4;

#define MFMA16(A, B, C) __builtin_amdgcn_mfma_f32_16x16x32_f16((A), (B), (C), 0, 0, 0)

// ---------------- e_sq pre-pass (exact fp32) ----------------
__global__ __launch_bounds__(256) void esq_kernel(const float* __restrict__ embed,
                                                  float* __restrict__ esq, int K) {
    int gid  = blockIdx.x * blockDim.x + threadIdx.x;
    int code = gid >> 6;
    int lane = threadIdx.x & 63;
    if (code >= K) return;
    float2 v = ((const float2*)(embed + (size_t)code * Cdim))[lane];
    float  s = fmaf(v.x, v.x, v.y * v.y);
    #pragma unroll
    for (int m = 32; m >= 1; m >>= 1) s += __shfl_xor(s, m, 64);
    if (lane == 0) esq[code] = s;
}

__device__ __forceinline__ void cvt8s(float4 a, float4 b, float scale,
                                      f16x8& h, f16x8& lo) {
    float v[8] = {a.x, a.y, a.z, a.w, b.x, b.y, b.z, b.w};
    #pragma unroll
    for (int i = 0; i < 8; ++i) {
        float s = v[i] * scale;
        f16 hh = (f16)s;
        h[i]  = hh;
        lo[i] = (f16)(s - (float)hh);
    }
}

// ---- codebook -> 16x16x32-fragment image, wave-linear lane order ----
// A-frag: lane l holds e[base + (l&15)][ks*32 + (l>>4)*8 .. +8]
// hi: IMG_OFF + ch*16384 + nt*4096 + ks*1024 + ((l>>4)*16 + (l&15))*16; lo +8192
__global__ __launch_bounds__(256) void bconv_kernel(const float* __restrict__ embed,
                                                    char* __restrict__ ws) {
    int t    = blockIdx.x * 256 + threadIdx.x;   // 16384 threads
    int code = t >> 4;
    int seg  = t & 15;
    int ks   = seg >> 2;
    int kseg = seg & 3;
    int ch = code >> 5, nt = (code >> 4) & 1, lr = code & 15;
    const float4* p = (const float4*)(embed + (size_t)code * Cdim + ks * 32 + kseg * 8);
    f16x8 h, lo;
    cvt8s(p[0], p[1], 1.0f, h, lo);
    size_t base = (size_t)IMG_OFF + (size_t)ch * CHUNK_BYTES
                + nt * 4096 + ks * 1024 + (kseg * 16 + lr) * 16;
    *(f16x8*)(ws + base)        = h;
    *(f16x8*)(ws + base + 8192) = lo;
}

// ---------------- async global->LDS 16B ----------------
__device__ __forceinline__ void gll16(const void* g, void* l) {
    __builtin_amdgcn_global_load_lds(
        (const __attribute__((address_space(1))) unsigned int*)g,
        (__attribute__((address_space(3))) unsigned int*)l, 16, 0, 0);
}

__global__ __launch_bounds__(THREADS, 2) void vq_kernel(
    const float* __restrict__ x, const float* __restrict__ embed,
    const char* __restrict__ ws, float* __restrict__ outq,
    float* __restrict__ outi) {

    __shared__ __align__(16) char  Bb[3][CHUNK_BYTES];   // 48KB ring
    __shared__ __align__(16) float esq_lds[KCODES];      // 4KB

    const int tid  = threadIdx.x;
    const int wid  = tid >> 6;          // wave 0..3
    const int l    = tid & 63;
    const int lr   = l & 15;            // x-row within 16-tile
    const int lg   = l >> 4;            // k-seg (in) / code-subrow (out)
    const int wr   = wid & 1;           // row group (64 rows)
    const int nt   = wid >> 1;          // code half of each chunk (16 codes)
    const int row0 = blockIdx.x * BROWS;

    // ---- prologue DMA: esq FIRST, then chunks 0,1 (9 outstanding) ----
    gll16(ws + wid * 1024 + (size_t)l * 16, (char*)esq_lds + wid * 1024);
    #pragma unroll
    for (int b = 0; b < 2; ++b) {
        const char* src = ws + IMG_OFF + b * CHUNK_BYTES + wid * 4096 + (size_t)l * 16;
        char*       dst = &Bb[b][wid * 4096];
        #pragma unroll
        for (int i = 0; i < 4; ++i) gll16(src + i * 1024, dst + i * 1024);
    }

    // ---- x rows -> B-fragments (2*xh, 2*xl): 4 rt-tiles of 16 rows ----
    f16x8 bxh[4][4], bxl[4][4];
    #pragma unroll
    for (int rt = 0; rt < 4; ++rt) {
        const float* xr = x + (size_t)(row0 + wr * 64 + rt * 16 + lr) * Cdim + lg * 8;
        #pragma unroll
        for (int ks = 0; ks < 4; ++ks) {
            float4 v0 = *(const float4*)(xr + ks * 32);
            float4 v1 = *(const float4*)(xr + ks * 32 + 4);
            cvt8s(v0, v1, 2.0f, bxh[rt][ks], bxl[rt][ks]);
        }
    }

    float best[4];
    int   bidx[4];
    #pragma unroll
    for (int rt = 0; rt < 4; ++rt) { best[rt] = -FLT_MAX; bidx[rt] = 0; }

    int cur = 0, pf = 2;

    // compute chunk ch into acc[4]; ring protocol inside (1 barrier/chunk)
    auto compute = [&](int ch, f32x4* acc) {
        // chunk ch's DMA issued 2 iterations ago -> this wait is ~free.
        if (ch == NCH - 1) asm volatile("s_waitcnt vmcnt(0)" ::: "memory");
        else               asm volatile("s_waitcnt vmcnt(4)" ::: "memory");
        __builtin_amdgcn_s_barrier();   // ch resident block-wide; slot pf free

        if (ch + 2 < NCH) {             // issue chunk ch+2 into freed slot
            const char* src = ws + IMG_OFF + (size_t)(ch + 2) * CHUNK_BYTES
                            + wid * 4096 + (size_t)l * 16;
            char* dst = &Bb[0][0] + (size_t)pf * CHUNK_BYTES + wid * 4096;
            #pragma unroll
            for (int i = 0; i < 4; ++i) gll16(src + i * 1024, dst + i * 1024);
        }

        #pragma unroll
        for (int rt = 0; rt < 4; ++rt) acc[rt] = (f32x4){0.f, 0.f, 0.f, 0.f};

        const char* bb = &Bb[0][0] + (size_t)cur * CHUNK_BYTES
                       + nt * 4096 + (size_t)l * 16;
        #pragma unroll
        for (int ks = 0; ks < 4; ++ks) {
            f16x8 eh = *(const f16x8*)(bb + ks * 1024);
            f16x8 el = *(const f16x8*)(bb + ks * 1024 + 8192);
            __builtin_amdgcn_s_setprio(1);
            #pragma unroll
            for (int rt = 0; rt < 4; ++rt) acc[rt] = MFMA16(eh, bxh[rt][ks], acc[rt]);
            #pragma unroll
            for (int rt = 0; rt < 4; ++rt) acc[rt] = MFMA16(eh, bxl[rt][ks], acc[rt]);
            #pragma unroll
            for (int rt = 0; rt < 4; ++rt) acc[rt] = MFMA16(el, bxh[rt][ks], acc[rt]);
            __builtin_amdgcn_s_setprio(0);
        }

        cur = (cur == 2) ? 0 : cur + 1;
        pf  = (pf  == 2) ? 0 : pf  + 1;
    };

    // score chunk ch (s = 2*dot - e^2, codes ascend, strict >)
    auto score = [&](int ch, const f32x4* acc) {
        const int cb = ch * CH + nt * 16 + lg * 4;
        float4 e4 = *(const float4*)&esq_lds[cb];
        #pragma unroll
        for (int rt = 0; rt < 4; ++rt)
            #pragma unroll
            for (int j = 0; j < 4; ++j) {
                float s = acc[rt][j] - ((const float*)&e4)[j];
                if (s > best[rt]) { best[rt] = s; bidx[rt] = cb + j; }
            }
    };

    f32x4 accA[4], accB[4];
    compute(0, accA);
    #pragma unroll 1
    for (int b = 0; b < 15; ++b) {
        compute(2 * b + 1, accB);
        score  (2 * b,     accA);       // hides in chunk 2b+1's MFMA shadow
        compute(2 * b + 2, accA);
        score  (2 * b + 1, accB);
    }
    compute(31, accB);
    score  (30, accA);
    score  (31, accB);

    // ---- epilogue: reuse ring LDS for merge buffers ----
    __syncthreads();
    float* mrgv    = (float*)&Bb[0][0];        // [2][128]
    int*   mrgi    = (int*)  &Bb[0][4096];     // [2][128]
    int*   winners = (int*)  &Bb[0][8192];     // [128]

    #pragma unroll
    for (int rt = 0; rt < 4; ++rt) {
        float bs = best[rt]; int bi = bidx[rt];
        #pragma unroll
        for (int m = 16; m <= 32; m <<= 1) {
            float vs = __shfl_xor(bs, m, 64);
            int   vi = __shfl_xor(bi, m, 64);
            if (vs > bs || (vs == bs && vi < bi)) { bs = vs; bi = vi; }
        }
        if (lg == 0) {
            mrgv[nt * BROWS + wr * 64 + rt * 16 + lr] = bs;
            mrgi[nt * BROWS + wr * 64 + rt * 16 + lr] = bi;
        }
    }
    __syncthreads();
    if (tid < BROWS) {
        float v0 = mrgv[tid];         int i0 = mrgi[tid];
        float v1 = mrgv[BROWS + tid]; int i1 = mrgi[BROWS + tid];
        int bi = (v1 > v0 || (v1 == v0 && i1 < i0)) ? i1 : i0;
        winners[tid] = bi;
        outi[row0 + tid] = (float)bi;
    }
    __syncthreads();

    // ---- gather quantized = embed[winner] (exact fp32 copy) ----
    #pragma unroll
    for (int i = 0; i < 16; ++i) {
        int pos = i * THREADS + tid;
        int r = pos >> 5, c4 = pos & 31;
        int idx = winners[r];
        float4 v = ((const float4*)(embed + (size_t)idx * Cdim))[c4];
        ((float4*)(outq + (size_t)(row0 + r) * Cdim))[c4] = v;
    }
}

extern "C" void kernel_launch(void* const* d_in, const int* in_sizes, int n_in,
                              void* d_out, int out_size, void* d_ws, size_t ws_size,
                              hipStream_t stream) {
    const float* x     = (const float*)d_in[0];
    const float* embed = (const float*)d_in[1];
    const int M = in_sizes[0] / Cdim;   // 65536
    const int K = in_sizes[1] / Cdim;   // 1024
    float* outq = (float*)d_out;
    float* outi = outq + (size_t)M * Cdim;

    esq_kernel <<<K / 4, 256, 0, stream>>>(embed, (float*)d_ws, K);
    bconv_kernel<<<64, 256, 0, stream>>>(embed, (char*)d_ws);
    vq_kernel  <<<M / BROWS, THREADS, 0, stream>>>(x, embed, (const char*)d_ws,
                                                   outq, outi);
}